// Round 4
// baseline (276.789 us; speedup 1.0000x reference)
//
#include <hip/hip_runtime.h>

// Match numpy rounding: no fma contraction anywhere in this file.
#pragma clang fp contract(off)

#define NCLS 22
#define NPAIR 11        // two classes packed per u32 (low/high ushort)
#define WS_ 80
#define P 4800          // 60*80
#define NBATCH 2
#define H 480
#define W 640
#define EPSF 1e-8f

#define JTILES 19       // ceil(P/256)
#define ICHUNKS 50
#define ILEN 96         // P / ICHUNKS

// ---------------- kernel A: gather subsampled data + zero hough ----------------
// packed[t] = {u, v, nrm, bitcast(lab)};  pos[t] = {px, py};  z_s[t] = z
// hough is packed: u32[n][pair][j], pair p = classes (2p low, 2p+1 high).
// Counts <= 4800 < 2^16 so halves never carry; packed atomicAdd is exact.
__global__ void prep_kernel(const int* __restrict__ label,
                            const float* __restrict__ vp,
                            float4* __restrict__ packed,
                            float2* __restrict__ pos,
                            float* __restrict__ z_s,
                            int4* __restrict__ hough4) {
    int t = blockIdx.x * blockDim.x + threadIdx.x;
    // zero the packed hough accumulator (ws is poisoned 0xAA before every launch)
    const int nthreads = gridDim.x * blockDim.x;
    const int HTOT4 = NBATCH * NPAIR * P / 4;   // 26400 int4
    for (int q = t; q < HTOT4; q += nthreads) hough4[q] = make_int4(0, 0, 0, 0);

    if (t >= NBATCH * P) return;
    int n = t / P, p = t % P;
    int hs = p / WS_, ws = p % WS_;
    int y = hs * 8, x = ws * 8;
    int lab = label[((size_t)n * H + y) * W + x];
    const size_t HW = (size_t)H * W;
    size_t base = ((size_t)n * (3 * NCLS) + 3 * lab) * HW + (size_t)y * W + x;
    float u = vp[base];
    float v = vp[base + HW];
    float z = vp[base + 2 * HW];
    float nrm = sqrtf(u * u + v * v) + EPSF;    // exact, same as reference
    packed[t] = make_float4(u, v, nrm, __int_as_float(lab));
    pos[t] = make_float2((float)x, (float)y);   // exact small ints
    z_s[t] = z;
}

// ---------------- kernel B: vote + per-class histogram over centers j ----------
// grid (JTILES, ICHUNKS, NBATCH), block 256. Thread owns center j; loop over
// i-chunk staged in LDS (uniform broadcast reads, zero global loads in loop).
__global__ void __launch_bounds__(256) vote_kernel(
        const float4* __restrict__ packed,
        const float2* __restrict__ pos,
        unsigned int* __restrict__ hough) {
    __shared__ float4 sdat[ILEN];
    __shared__ float2 spos[ILEN];
    __shared__ unsigned int hist[NPAIR][256];   // two ushort class counters per u32
    int tid = threadIdx.x;
    int j = blockIdx.x * 256 + tid;           // may be >= P in last tile
    int n = blockIdx.z;
    int i0 = blockIdx.y * ILEN;

    if (tid < ILEN) {
        sdat[tid] = packed[n * P + i0 + tid];
        spos[tid] = pos[n * P + i0 + tid];
    }
    for (int p = 0; p < NPAIR; ++p) hist[p][tid] = 0;
    __syncthreads();

    int jc = j < P ? j : 0;
    float pxj = (float)((jc % WS_) * 8);
    float pyj = (float)((jc / WS_) * 8);

    #pragma unroll 4
    for (int ii = 0; ii < ILEN; ++ii) {
        float4 d = sdat[ii];
        int lab = __float_as_int(d.w);
        if (lab == 0) continue;               // uniform branch
        float2 pp = spos[ii];
        float dx = pxj - pp.x;
        float dy = pyj - pp.y;
        float d2 = dx * dx + dy * dy;         // exact (small ints)
        float dist = sqrtf(d2);
        float num = d.x * dx + d.y * dy;
        float den = d.z * (dist + EPSF);
        float cosang = num / den;             // IEEE divide, matches numpy
        unsigned int vote = (cosang >= 0.9f) && (d2 > 0.0f);
        // lab is wave-uniform -> shift amount is scalar
        hist[lab >> 1][tid] += vote << ((lab & 1) * 16);
    }
    __syncthreads();
    if (j < P) {
        for (int p = 0; p < NPAIR; ++p) {
            unsigned int h = hist[p][tid];
            if (h) atomicAdd(&hough[((size_t)n * NPAIR + p) * P + j], h);
        }
    }
}

// ---------------- kernel C: argmax + counts / inliers / z-mean / epilogue ------
__global__ void __launch_bounds__(256) final_kernel(
        const unsigned int* __restrict__ hough,
        const float4* __restrict__ packed,
        const float2* __restrict__ pos,
        const float* __restrict__ z_s,
        const float* __restrict__ extents,
        const float* __restrict__ meta,
        float* __restrict__ out) {
    int row_id = blockIdx.x;                  // n*NCLS + c
    int n = row_id / NCLS, c = row_id % NCLS;
    int tid = threadIdx.x;                    // 256

    // --- phase 1: argmax over j (first-max tie-break, matches jnp.argmax) ---
    const unsigned int* row = &hough[((size_t)n * NPAIR + (c >> 1)) * P];
    const int sh = (c & 1) * 16;
    int bi = tid;
    int bv = (int)((row[tid] >> sh) & 0xFFFFu);
    for (int jj = tid + 256; jj < P; jj += 256) {
        int v = (int)((row[jj] >> sh) & 0xFFFFu);
        if (v > bv) { bv = v; bi = jj; }      // keeps smallest index per stride
    }
    __shared__ int sv[256], si[256];
    sv[tid] = bv; si[tid] = bi;
    __syncthreads();
    for (int s = 128; s > 0; s >>= 1) {
        if (tid < s) {
            int v2 = sv[tid + s], i2 = si[tid + s];
            if (v2 > sv[tid] || (v2 == sv[tid] && i2 < si[tid])) {
                sv[tid] = v2; si[tid] = i2;
            }
        }
        __syncthreads();
    }
    int b = si[0];
    float mv = (float)sv[0];
    __syncthreads();

    // --- phase 2: counts, inliers at best, z sum ---
    float pxb = (float)((b % WS_) * 8);
    float pyb = (float)((b / WS_) * 8);
    int cnt = 0, nin = 0;
    float zs = 0.0f;
    for (int i = tid; i < P; i += 256) {
        float4 d = packed[n * P + i];
        int lab = __float_as_int(d.w);
        if (lab != c) continue;
        cnt++;
        if (c == 0) continue;                 // fg condition kills votes anyway
        float2 pp = pos[n * P + i];
        float dx = pxb - pp.x;
        float dy = pyb - pp.y;
        float d2 = dx * dx + dy * dy;
        float dist = sqrtf(d2);
        float num = d.x * dx + d.y * dy;
        float den = d.z * (dist + EPSF);
        float cosang = num / den;
        if ((cosang >= 0.9f) && (d2 > 0.0f)) {
            nin++;
            zs += z_s[n * P + i];
        }
    }
    __shared__ int sc[256], sn[256];
    __shared__ float sz[256];
    sc[tid] = cnt; sn[tid] = nin; sz[tid] = zs;
    __syncthreads();
    for (int s = 128; s > 0; s >>= 1) {
        if (tid < s) {
            sc[tid] += sc[tid + s];
            sn[tid] += sn[tid + s];
            sz[tid] += sz[tid + s];
        }
        __syncthreads();
    }
    if (tid == 0) {
        float cntf = (float)sc[0];
        float ninf = (float)sn[0];
        float z_mean = sz[0] / fmaxf(ninf, 1.0f);
        float zc = fmaxf(z_mean, 0.001f);
        bool valid = (cntf * 64.0f >= 500.0f) && (mv >= 10.0f)
                     && (mv >= 0.02f * cntf) && (c > 0);
        float vm = valid ? 1.0f : 0.0f;
        float fx  = meta[n * 9 + 0];
        float ppx = meta[n * 9 + 2];
        float fy  = meta[n * 9 + 4];
        float ppy = meta[n * 9 + 5];
        float ex = extents[c * 3 + 0];
        float ey = extents[c * 3 + 1];
        float bw = ex * fx / zc;
        float bh = ey * fy / zc;
        float cx = pxb, cy = pyb;
        float tx = (cx - ppx) * zc / fx;
        float ty = (cy - ppy) * zc / fy;
        float* box = out + (size_t)row_id * 7;
        box[0] = (float)n * vm;
        box[1] = (float)c * vm;
        box[2] = (cx - bw / 2.0f) * vm;
        box[3] = (cy - bh / 2.0f) * vm;
        box[4] = (cx + bw / 2.0f) * vm;
        box[5] = (cy + bh / 2.0f) * vm;
        box[6] = mv * vm;
        float* pose = out + (size_t)NBATCH * NCLS * 7 + (size_t)row_id * 7;
        pose[0] = vm;
        pose[1] = 0.0f;
        pose[2] = 0.0f;
        pose[3] = 0.0f;
        pose[4] = tx * vm;
        pose[5] = ty * vm;
        pose[6] = zc * vm;
    }
}

extern "C" void kernel_launch(void* const* d_in, const int* in_sizes, int n_in,
                              void* d_out, int out_size, void* d_ws, size_t ws_size,
                              hipStream_t stream) {
    const int*   label   = (const int*)d_in[0];     // (N,H,W) int32
    const float* vp      = (const float*)d_in[1];   // (N,66,H,W) f32
    const float* extents = (const float*)d_in[2];   // (22,3) f32
    // d_in[3] = poses (unused)
    const float* meta    = (const float*)d_in[4];   // (N,9) f32
    float* out = (float*)d_out;                     // 616 f32

    char* ws = (char*)d_ws;
    // layout (bytes): packed[9600]f4 (153600) | pos[9600]f2 (76800) |
    //                 z_s[9600]f32 (38400) | hough packed u32[2][11][4800] (422400)
    float4* packed = (float4*)(ws + 0);
    float2* pos    = (float2*)(ws + 153600);
    float*  z_s    = (float*)(ws + 153600 + 76800);
    unsigned int* hough = (unsigned int*)(ws + 153600 + 76800 + 38400);

    prep_kernel<<<(NBATCH * P + 255) / 256, 256, 0, stream>>>(
        label, vp, packed, pos, z_s, (int4*)hough);

    dim3 vgrid(JTILES, ICHUNKS, NBATCH);
    vote_kernel<<<vgrid, 256, 0, stream>>>(packed, pos, hough);

    final_kernel<<<NBATCH * NCLS, 256, 0, stream>>>(hough, packed, pos, z_s,
                                                    extents, meta, out);
}